// Round 6
// baseline (83.527 us; speedup 1.0000x reference)
//
#include <hip/hip_runtime.h>

// Problem constants (from reference setup_inputs): B=8, L=4096, D=256, f32.
#define BATCH 8
#define SEQ   4096
#define DIM   256

// Native clang vector type — required by __builtin_nontemporal_store.
typedef float floatx4 __attribute__((ext_vector_type(4)));

// Tile decomposition: NT tiles of T timesteps per batch; one wave per tile,
// 64 lanes x 4 consecutive d-columns (float4 = 16B/lane loads).
//
// R5 lesson: latency-bound at ~1 outstanding wave-load per wave and only
// 2 waves/SIMD. Fix BOTH: NT=512 -> 1024 blocks (16 waves/CU offered,
// __launch_bounds__(256,4)) and an explicit 2-phase register double-buffer
// (load phase s+1 issued before computing phase s; all indices static
// after full unroll) so every wave keeps ~8KB outstanding at all times.

// ---------------------------------------------------------------------------
// Kernel 1: per-(b, tile) affine aggregate.
// ---------------------------------------------------------------------------
template <int NT, int T, int G>
__global__ __launch_bounds__(256, 4) void k_tile_agg(
    const float* __restrict__ Ar, const float* __restrict__ Ai,
    const float* __restrict__ Xr, const float* __restrict__ Xi,
    float4* __restrict__ agg)
{
    constexpr int NS = T / G;                 // pipeline stages
    int wave = threadIdx.x >> 6;
    int lane = threadIdx.x & 63;
    int tile = blockIdx.x * 4 + wave;         // in [0, BATCH*NT)
    int b = tile / NT;
    int j = tile - b * NT;
    int d = lane * 4;

    size_t base = ((size_t)b * SEQ + (size_t)j * T) * DIM + d;

    float ar[4], ai[4], xr[4], xi[4];
#pragma unroll
    for (int k = 0; k < 4; ++k) { ar[k] = 1.f; ai[k] = 0.f; xr[k] = 0.f; xi[k] = 0.f; }

    float4 P0[4][G], P1[4][G];                // [array][g], two phases

    auto LOAD = [&](float4 (&B)[4][G], int t0) {
#pragma unroll
        for (int g = 0; g < G; ++g) {
            size_t idx = base + (size_t)(t0 + g) * DIM;
            B[0][g] = *(const float4*)(Ar + idx);
            B[1][g] = *(const float4*)(Ai + idx);
            B[2][g] = *(const float4*)(Xr + idx);
            B[3][g] = *(const float4*)(Xi + idx);
        }
    };
    auto STEP = [&](float4 (&B)[4][G]) {
#pragma unroll
        for (int g = 0; g < G; ++g) {
            const float* pab = (const float*)&B[0][g];
            const float* pai = (const float*)&B[1][g];
            const float* pxr = (const float*)&B[2][g];
            const float* pxi = (const float*)&B[3][g];
#pragma unroll
            for (int k = 0; k < 4; ++k) {
                float a_r = pab[k], a_i = pai[k], x_r = pxr[k], x_i = pxi[k];
                float nar = a_r * ar[k] - a_i * ai[k];
                float nai = a_r * ai[k] + a_i * ar[k];
                float nxr = a_r * xr[k] - a_i * xi[k] + x_r;
                float nxi = a_r * xi[k] + a_i * xr[k] + x_i;
                ar[k] = nar; ai[k] = nai; xr[k] = nxr; xi[k] = nxi;
            }
        }
    };

    LOAD(P0, 0);
#pragma unroll
    for (int s = 0; s < NS; ++s) {
        if ((s & 1) == 0) {
            if (s + 1 < NS) LOAD(P1, (s + 1) * G);
            STEP(P0);
        } else {
            if (s + 1 < NS) LOAD(P0, (s + 1) * G);
            STEP(P1);
        }
    }

    size_t o = ((size_t)b * NT + j) * DIM + d;
#pragma unroll
    for (int k = 0; k < 4; ++k)
        agg[o + k] = make_float4(ar[k], ai[k], xr[k], xi[k]);
}

// ---------------------------------------------------------------------------
// Kernel 2: wave-parallel exclusive scan of tile aggregates along j.
// One wave per (b,d) column; lane owns NTPL = NT/64 consecutive tiles.
// ---------------------------------------------------------------------------
template <int NT>
__global__ __launch_bounds__(256) void k_scan_agg(float4* __restrict__ agg)
{
    constexpr int NTPL = NT / 64;
    int lane = threadIdx.x & 63;
    int col  = blockIdx.x * 4 + (threadIdx.x >> 6);   // in [0, BATCH*DIM)
    int b = col >> 8;          // / DIM
    int d = col & 255;         // % DIM

    float4 v[NTPL];
    float lar = 1.f, lai = 0.f, lxr = 0.f, lxi = 0.f;
#pragma unroll
    for (int m = 0; m < NTPL; ++m) {
        v[m] = agg[((size_t)b * NT + lane * NTPL + m) * DIM + d];
        float nar = v[m].x * lar - v[m].y * lai;
        float nai = v[m].x * lai + v[m].y * lar;
        float nxr = v[m].x * lxr - v[m].y * lxi + v[m].z;
        float nxi = v[m].x * lxi + v[m].y * lxr + v[m].w;
        lar = nar; lai = nai; lxr = nxr; lxi = nxi;
    }

    float ar = lar, ai = lai, xr = lxr, xi = lxi;
#pragma unroll
    for (int off = 1; off < 64; off <<= 1) {
        float par = __shfl_up(ar, (unsigned)off, 64);
        float pai = __shfl_up(ai, (unsigned)off, 64);
        float pxr = __shfl_up(xr, (unsigned)off, 64);
        float pxi = __shfl_up(xi, (unsigned)off, 64);
        if (lane >= off) {
            float nar = ar * par - ai * pai;
            float nai = ar * pai + ai * par;
            float nxr = ar * pxr - ai * pxi + xr;
            float nxi = ar * pxi + ai * pxr + xi;
            ar = nar; ai = nai; xr = nxr; xi = nxi;
        }
    }

    float ear = __shfl_up(ar, 1u, 64);
    float eai = __shfl_up(ai, 1u, 64);
    float exr = __shfl_up(xr, 1u, 64);
    float exi = __shfl_up(xi, 1u, 64);
    if (lane == 0) { ear = 1.f; eai = 0.f; exr = 0.f; exi = 0.f; }

#pragma unroll
    for (int m = 0; m < NTPL; ++m) {
        agg[((size_t)b * NT + lane * NTPL + m) * DIM + d] =
            make_float4(exr, exi, 0.f, 0.f);
        float nar = v[m].x * ear - v[m].y * eai;
        float nai = v[m].x * eai + v[m].y * ear;
        float nxr = v[m].x * exr - v[m].y * exi + v[m].z;
        float nxi = v[m].x * exi + v[m].y * exr + v[m].w;
        ear = nar; eai = nai; exr = nxr; exi = nxi;
    }
}

// ---------------------------------------------------------------------------
// Kernel 3: seed y from tile prefix, recompute recurrence, write out.
// Same 2-phase pipeline; output [B,L,D,2] = two contiguous float4 per lane
// per t-step, nontemporal (write-once; keep L3 for the inputs).
// ---------------------------------------------------------------------------
template <int NT, int T, int G>
__global__ __launch_bounds__(256, 4) void k_apply(
    const float* __restrict__ Ar, const float* __restrict__ Ai,
    const float* __restrict__ Xr, const float* __restrict__ Xi,
    const float4* __restrict__ agg, float* __restrict__ outf)
{
    constexpr int NS = T / G;
    int wave = threadIdx.x >> 6;
    int lane = threadIdx.x & 63;
    int tile = blockIdx.x * 4 + wave;
    int b = tile / NT;
    int j = tile - b * NT;
    int d = lane * 4;

    float yr[4], yi[4];
    size_t o = ((size_t)b * NT + j) * DIM + d;
#pragma unroll
    for (int k = 0; k < 4; ++k) {
        float4 p = agg[o + k];
        yr[k] = p.x; yi[k] = p.y;
    }

    size_t base = ((size_t)b * SEQ + (size_t)j * T) * DIM + d;

    float4 P0[4][G], P1[4][G];

    auto LOAD = [&](float4 (&B)[4][G], int t0) {
#pragma unroll
        for (int g = 0; g < G; ++g) {
            size_t idx = base + (size_t)(t0 + g) * DIM;
            B[0][g] = *(const float4*)(Ar + idx);
            B[1][g] = *(const float4*)(Ai + idx);
            B[2][g] = *(const float4*)(Xr + idx);
            B[3][g] = *(const float4*)(Xi + idx);
        }
    };
    auto STEP = [&](float4 (&B)[4][G], int t0) {
#pragma unroll
        for (int g = 0; g < G; ++g) {
            const float* pab = (const float*)&B[0][g];
            const float* pai = (const float*)&B[1][g];
            const float* pxr = (const float*)&B[2][g];
            const float* pxi = (const float*)&B[3][g];
#pragma unroll
            for (int k = 0; k < 4; ++k) {
                float nyr = pab[k] * yr[k] - pai[k] * yi[k] + pxr[k];
                float nyi = pab[k] * yi[k] + pai[k] * yr[k] + pxi[k];
                yr[k] = nyr; yi[k] = nyi;
            }
            size_t idx = base + (size_t)(t0 + g) * DIM;
            floatx4 o1 = (floatx4){yr[0], yi[0], yr[1], yi[1]};
            floatx4 o2 = (floatx4){yr[2], yi[2], yr[3], yi[3]};
            float* po = outf + 2 * idx;
            __builtin_nontemporal_store(o1, (floatx4*)(po));
            __builtin_nontemporal_store(o2, (floatx4*)(po + 4));
        }
    };

    LOAD(P0, 0);
#pragma unroll
    for (int s = 0; s < NS; ++s) {
        if ((s & 1) == 0) {
            if (s + 1 < NS) LOAD(P1, (s + 1) * G);
            STEP(P0, s * G);
        } else {
            if (s + 1 < NS) LOAD(P0, (s + 1) * G);
            STEP(P1, s * G);
        }
    }
}

extern "C" void kernel_launch(void* const* d_in, const int* in_sizes, int n_in,
                              void* d_out, int out_size, void* d_ws, size_t ws_size,
                              hipStream_t stream)
{
    const float* Ar = (const float*)d_in[0];
    const float* Ai = (const float*)d_in[1];
    const float* Xr = (const float*)d_in[2];
    const float* Xi = (const float*)d_in[3];
    float* outf = (float*)d_out;
    float4* agg = (float4*)d_ws;

    dim3 block(256);

    if (ws_size >= (size_t)BATCH * 512 * DIM * sizeof(float4)) {
        constexpr int NT = 512, T = SEQ / 512;   // T = 8
        dim3 grid1((BATCH * NT) / 4);            // 1024 blocks
        k_tile_agg<NT, T, 2><<<grid1, block, 0, stream>>>(Ar, Ai, Xr, Xi, agg);
        k_scan_agg<NT><<<(BATCH * DIM) / 4, block, 0, stream>>>(agg);
        k_apply<NT, T, 2><<<grid1, block, 0, stream>>>(Ar, Ai, Xr, Xi, agg, outf);
    } else if (ws_size >= (size_t)BATCH * 256 * DIM * sizeof(float4)) {
        constexpr int NT = 256, T = SEQ / 256;   // T = 16
        dim3 grid1((BATCH * NT) / 4);
        k_tile_agg<NT, T, 2><<<grid1, block, 0, stream>>>(Ar, Ai, Xr, Xi, agg);
        k_scan_agg<NT><<<(BATCH * DIM) / 4, block, 0, stream>>>(agg);
        k_apply<NT, T, 2><<<grid1, block, 0, stream>>>(Ar, Ai, Xr, Xi, agg, outf);
    } else {
        constexpr int NT = 64, T = SEQ / 64;     // T = 64
        dim3 grid1((BATCH * NT) / 4);
        k_tile_agg<NT, T, 2><<<grid1, block, 0, stream>>>(Ar, Ai, Xr, Xi, agg);
        k_scan_agg<NT><<<(BATCH * DIM) / 4, block, 0, stream>>>(agg);
        k_apply<NT, T, 2><<<grid1, block, 0, stream>>>(Ar, Ai, Xr, Xi, agg, outf);
    }
}

// Round 7
// 73.354 us; speedup vs baseline: 1.1387x; 1.1387x over previous
//
#include <hip/hip_runtime.h>

// Problem constants (from reference setup_inputs): B=8, L=4096, D=256, f32.
#define BATCH 8
#define SEQ   4096
#define DIM   256

// Native clang vector type — required by __builtin_nontemporal_store.
typedef float floatx4 __attribute__((ext_vector_type(4)));

// R6 lesson: compiler defeats deep register double-buffers (VGPR stayed 64);
// the winning knob is resident-wave count (TLP), not per-wave ILP.
// Structure: NT tiles of T steps per batch; each tile is handled by TWO
// waves (128 threads), each lane owning 2 d-columns (float2 = 8B/lane).
// Block = 256 threads = 2 tiles. NT=512 -> grid 2048 blocks = 8 blocks/CU;
// __launch_bounds__(256,8) caps VGPR at 64 -> 32 waves/CU resident.

// ---------------------------------------------------------------------------
// Kernel 1: per-(b, tile) affine aggregate. 2 d-columns/thread via float2.
// ---------------------------------------------------------------------------
template <int NT, int T, int G>
__global__ __launch_bounds__(256, 8) void k_tile_agg(
    const float* __restrict__ Ar, const float* __restrict__ Ai,
    const float* __restrict__ Xr, const float* __restrict__ Xi,
    float4* __restrict__ agg)
{
    constexpr int NS = T / G;                 // pipeline stages
    int half = threadIdx.x >> 7;              // which tile within block (0/1)
    int wl   = threadIdx.x & 127;             // position within tile-pair
    int tile = blockIdx.x * 2 + half;         // in [0, BATCH*NT)
    int b = tile / NT;
    int j = tile - b * NT;
    int d = wl * 2;

    size_t base = ((size_t)b * SEQ + (size_t)j * T) * DIM + d;

    float ar[2], ai[2], xr[2], xi[2];
#pragma unroll
    for (int k = 0; k < 2; ++k) { ar[k] = 1.f; ai[k] = 0.f; xr[k] = 0.f; xi[k] = 0.f; }

    float2 P0[4][G], P1[4][G];                // [array][g], two phases

    auto LOAD = [&](float2 (&B)[4][G], int t0) {
#pragma unroll
        for (int g = 0; g < G; ++g) {
            size_t idx = base + (size_t)(t0 + g) * DIM;
            B[0][g] = *(const float2*)(Ar + idx);
            B[1][g] = *(const float2*)(Ai + idx);
            B[2][g] = *(const float2*)(Xr + idx);
            B[3][g] = *(const float2*)(Xi + idx);
        }
    };
    auto STEP = [&](float2 (&B)[4][G]) {
#pragma unroll
        for (int g = 0; g < G; ++g) {
            const float* pab = (const float*)&B[0][g];
            const float* pai = (const float*)&B[1][g];
            const float* pxr = (const float*)&B[2][g];
            const float* pxi = (const float*)&B[3][g];
#pragma unroll
            for (int k = 0; k < 2; ++k) {
                float a_r = pab[k], a_i = pai[k], x_r = pxr[k], x_i = pxi[k];
                float nar = a_r * ar[k] - a_i * ai[k];
                float nai = a_r * ai[k] + a_i * ar[k];
                float nxr = a_r * xr[k] - a_i * xi[k] + x_r;
                float nxi = a_r * xi[k] + a_i * xr[k] + x_i;
                ar[k] = nar; ai[k] = nai; xr[k] = nxr; xi[k] = nxi;
            }
        }
    };

    LOAD(P0, 0);
#pragma unroll
    for (int s = 0; s < NS; ++s) {
        if ((s & 1) == 0) {
            if (s + 1 < NS) LOAD(P1, (s + 1) * G);
            STEP(P0);
        } else {
            if (s + 1 < NS) LOAD(P0, (s + 1) * G);
            STEP(P1);
        }
    }

    size_t o = ((size_t)b * NT + j) * DIM + d;
    agg[o]     = make_float4(ar[0], ai[0], xr[0], xi[0]);
    agg[o + 1] = make_float4(ar[1], ai[1], xr[1], xi[1]);
}

// ---------------------------------------------------------------------------
// Kernel 2: wave-parallel exclusive scan of tile aggregates along j.
// One wave per (b,d) column; lane owns NTPL = NT/64 consecutive tiles.
// ---------------------------------------------------------------------------
template <int NT>
__global__ __launch_bounds__(256) void k_scan_agg(float4* __restrict__ agg)
{
    constexpr int NTPL = NT / 64;
    int lane = threadIdx.x & 63;
    int col  = blockIdx.x * 4 + (threadIdx.x >> 6);   // in [0, BATCH*DIM)
    int b = col >> 8;          // / DIM
    int d = col & 255;         // % DIM

    float4 v[NTPL];
    float lar = 1.f, lai = 0.f, lxr = 0.f, lxi = 0.f;
#pragma unroll
    for (int m = 0; m < NTPL; ++m) {
        v[m] = agg[((size_t)b * NT + lane * NTPL + m) * DIM + d];
        float nar = v[m].x * lar - v[m].y * lai;
        float nai = v[m].x * lai + v[m].y * lar;
        float nxr = v[m].x * lxr - v[m].y * lxi + v[m].z;
        float nxi = v[m].x * lxi + v[m].y * lxr + v[m].w;
        lar = nar; lai = nai; lxr = nxr; lxi = nxi;
    }

    float ar = lar, ai = lai, xr = lxr, xi = lxi;
#pragma unroll
    for (int off = 1; off < 64; off <<= 1) {
        float par = __shfl_up(ar, (unsigned)off, 64);
        float pai = __shfl_up(ai, (unsigned)off, 64);
        float pxr = __shfl_up(xr, (unsigned)off, 64);
        float pxi = __shfl_up(xi, (unsigned)off, 64);
        if (lane >= off) {
            float nar = ar * par - ai * pai;
            float nai = ar * pai + ai * par;
            float nxr = ar * pxr - ai * pxi + xr;
            float nxi = ar * pxi + ai * pxr + xi;
            ar = nar; ai = nai; xr = nxr; xi = nxi;
        }
    }

    float ear = __shfl_up(ar, 1u, 64);
    float eai = __shfl_up(ai, 1u, 64);
    float exr = __shfl_up(xr, 1u, 64);
    float exi = __shfl_up(xi, 1u, 64);
    if (lane == 0) { ear = 1.f; eai = 0.f; exr = 0.f; exi = 0.f; }

#pragma unroll
    for (int m = 0; m < NTPL; ++m) {
        agg[((size_t)b * NT + lane * NTPL + m) * DIM + d] =
            make_float4(exr, exi, 0.f, 0.f);
        float nar = v[m].x * ear - v[m].y * eai;
        float nai = v[m].x * eai + v[m].y * ear;
        float nxr = v[m].x * exr - v[m].y * exi + v[m].z;
        float nxi = v[m].x * exi + v[m].y * exr + v[m].w;
        ear = nar; eai = nai; exr = nxr; exi = nxi;
    }
}

// ---------------------------------------------------------------------------
// Kernel 3: seed y from tile prefix, recompute recurrence, write out.
// Same 2-wave-per-tile split; per t each lane writes one contiguous
// 16B nontemporal store ((d,re),(d,im),(d+1,re),(d+1,im)).
// ---------------------------------------------------------------------------
template <int NT, int T, int G>
__global__ __launch_bounds__(256, 8) void k_apply(
    const float* __restrict__ Ar, const float* __restrict__ Ai,
    const float* __restrict__ Xr, const float* __restrict__ Xi,
    const float4* __restrict__ agg, float* __restrict__ outf)
{
    constexpr int NS = T / G;
    int half = threadIdx.x >> 7;
    int wl   = threadIdx.x & 127;
    int tile = blockIdx.x * 2 + half;
    int b = tile / NT;
    int j = tile - b * NT;
    int d = wl * 2;

    float yr[2], yi[2];
    size_t o = ((size_t)b * NT + j) * DIM + d;
    {
        float4 p0 = agg[o];
        float4 p1 = agg[o + 1];
        yr[0] = p0.x; yi[0] = p0.y;
        yr[1] = p1.x; yi[1] = p1.y;
    }

    size_t base = ((size_t)b * SEQ + (size_t)j * T) * DIM + d;

    float2 P0[4][G], P1[4][G];

    auto LOAD = [&](float2 (&B)[4][G], int t0) {
#pragma unroll
        for (int g = 0; g < G; ++g) {
            size_t idx = base + (size_t)(t0 + g) * DIM;
            B[0][g] = *(const float2*)(Ar + idx);
            B[1][g] = *(const float2*)(Ai + idx);
            B[2][g] = *(const float2*)(Xr + idx);
            B[3][g] = *(const float2*)(Xi + idx);
        }
    };
    auto STEP = [&](float2 (&B)[4][G], int t0) {
#pragma unroll
        for (int g = 0; g < G; ++g) {
            const float* pab = (const float*)&B[0][g];
            const float* pai = (const float*)&B[1][g];
            const float* pxr = (const float*)&B[2][g];
            const float* pxi = (const float*)&B[3][g];
#pragma unroll
            for (int k = 0; k < 2; ++k) {
                float nyr = pab[k] * yr[k] - pai[k] * yi[k] + pxr[k];
                float nyi = pab[k] * yi[k] + pai[k] * yr[k] + pxi[k];
                yr[k] = nyr; yi[k] = nyi;
            }
            size_t idx = base + (size_t)(t0 + g) * DIM;
            floatx4 o1 = (floatx4){yr[0], yi[0], yr[1], yi[1]};
            __builtin_nontemporal_store(o1, (floatx4*)(outf + 2 * idx));
        }
    };

    LOAD(P0, 0);
#pragma unroll
    for (int s = 0; s < NS; ++s) {
        if ((s & 1) == 0) {
            if (s + 1 < NS) LOAD(P1, (s + 1) * G);
            STEP(P0, s * G);
        } else {
            if (s + 1 < NS) LOAD(P0, (s + 1) * G);
            STEP(P1, s * G);
        }
    }
}

extern "C" void kernel_launch(void* const* d_in, const int* in_sizes, int n_in,
                              void* d_out, int out_size, void* d_ws, size_t ws_size,
                              hipStream_t stream)
{
    const float* Ar = (const float*)d_in[0];
    const float* Ai = (const float*)d_in[1];
    const float* Xr = (const float*)d_in[2];
    const float* Xi = (const float*)d_in[3];
    float* outf = (float*)d_out;
    float4* agg = (float4*)d_ws;

    dim3 block(256);

    if (ws_size >= (size_t)BATCH * 512 * DIM * sizeof(float4)) {
        constexpr int NT = 512, T = SEQ / 512;   // T = 8
        dim3 grid1((BATCH * NT) / 2);            // 2048 blocks -> 8/CU
        k_tile_agg<NT, T, 2><<<grid1, block, 0, stream>>>(Ar, Ai, Xr, Xi, agg);
        k_scan_agg<NT><<<(BATCH * DIM) / 4, block, 0, stream>>>(agg);
        k_apply<NT, T, 2><<<grid1, block, 0, stream>>>(Ar, Ai, Xr, Xi, agg, outf);
    } else if (ws_size >= (size_t)BATCH * 256 * DIM * sizeof(float4)) {
        constexpr int NT = 256, T = SEQ / 256;   // T = 16
        dim3 grid1((BATCH * NT) / 2);
        k_tile_agg<NT, T, 2><<<grid1, block, 0, stream>>>(Ar, Ai, Xr, Xi, agg);
        k_scan_agg<NT><<<(BATCH * DIM) / 4, block, 0, stream>>>(agg);
        k_apply<NT, T, 2><<<grid1, block, 0, stream>>>(Ar, Ai, Xr, Xi, agg, outf);
    } else {
        constexpr int NT = 64, T = SEQ / 64;     // T = 64
        dim3 grid1((BATCH * NT) / 2);
        k_tile_agg<NT, T, 2><<<grid1, block, 0, stream>>>(Ar, Ai, Xr, Xi, agg);
        k_scan_agg<NT><<<(BATCH * DIM) / 4, block, 0, stream>>>(agg);
        k_apply<NT, T, 2><<<grid1, block, 0, stream>>>(Ar, Ai, Xr, Xi, agg, outf);
    }
}

// Round 8
// 66.587 us; speedup vs baseline: 1.2544x; 1.1016x over previous
//
#include <hip/hip_runtime.h>

// Problem constants (from reference setup_inputs): B=8, L=4096, D=256, f32.
#define BATCH 8
#define SEQ   4096
#define DIM   256

// Native clang vector type — required by __builtin_nontemporal_store.
typedef float floatx4 __attribute__((ext_vector_type(4)));

// R7 lesson: k_tile_agg's time is invariant to vectorization, occupancy,
// tile size, and L3 residency — but k_apply (same loads, more stores, 2-wide
// plain recurrence) runs 2x faster. Hypothesis: the 4-wide coupled affine
// state chain is the limiter. Fix: compute the tile aggregate as TWO
// INDEPENDENT 2-wide chains:
//   A_prod: (pr,pi)   <- complex running product of a
//   X_agg:  (yr,yi)   <- plain recurrence y = a*y + x from y=0
// (X_agg of a tile IS y started from zero — identical result.)
// Inner loop shape is then literally k_apply's, which we know runs fast.

// ---------------------------------------------------------------------------
// Kernel 1: per-(b, tile) aggregate. Tile = 2 waves; 2 d-cols/lane (float2).
// ---------------------------------------------------------------------------
template <int NT, int T>
__global__ __launch_bounds__(256, 8) void k_tile_agg(
    const float* __restrict__ Ar, const float* __restrict__ Ai,
    const float* __restrict__ Xr, const float* __restrict__ Xi,
    float4* __restrict__ agg)
{
    int half = threadIdx.x >> 7;              // which tile within block (0/1)
    int wl   = threadIdx.x & 127;             // position within tile-pair
    int tile = blockIdx.x * 2 + half;         // in [0, BATCH*NT)
    int b = tile / NT;
    int j = tile - b * NT;
    int d = wl * 2;

    size_t base = ((size_t)b * SEQ + (size_t)j * T) * DIM + d;

    float pr[2], pi[2], yr[2], yi[2];
#pragma unroll
    for (int k = 0; k < 2; ++k) { pr[k] = 1.f; pi[k] = 0.f; yr[k] = 0.f; yi[k] = 0.f; }

#pragma unroll
    for (int t = 0; t < T; ++t) {
        size_t idx = base + (size_t)t * DIM;
        float2 a_re = *(const float2*)(Ar + idx);
        float2 a_im = *(const float2*)(Ai + idx);
        float2 x_re = *(const float2*)(Xr + idx);
        float2 x_im = *(const float2*)(Xi + idx);
        const float* par = (const float*)&a_re;
        const float* pai = (const float*)&a_im;
        const float* pxr = (const float*)&x_re;
        const float* pxi = (const float*)&x_im;
#pragma unroll
        for (int k = 0; k < 2; ++k) {
            float a_r = par[k], a_i = pai[k];
            // chain 1: running product of a
            float npr = a_r * pr[k] - a_i * pi[k];
            float npi = a_r * pi[k] + a_i * pr[k];
            pr[k] = npr; pi[k] = npi;
            // chain 2: plain recurrence from zero (independent of chain 1)
            float nyr = a_r * yr[k] - a_i * yi[k] + pxr[k];
            float nyi = a_r * yi[k] + a_i * yr[k] + pxi[k];
            yr[k] = nyr; yi[k] = nyi;
        }
    }

    size_t o = ((size_t)b * NT + j) * DIM + d;
    agg[o]     = make_float4(pr[0], pi[0], yr[0], yi[0]);
    agg[o + 1] = make_float4(pr[1], pi[1], yr[1], yi[1]);
}

// ---------------------------------------------------------------------------
// Kernel 2: wave-parallel exclusive scan of tile aggregates along j.
// One wave per (b,d) column; lane owns NTPL = NT/64 consecutive tiles.
// ---------------------------------------------------------------------------
template <int NT>
__global__ __launch_bounds__(256) void k_scan_agg(float4* __restrict__ agg)
{
    constexpr int NTPL = NT / 64;
    int lane = threadIdx.x & 63;
    int col  = blockIdx.x * 4 + (threadIdx.x >> 6);   // in [0, BATCH*DIM)
    int b = col >> 8;          // / DIM
    int d = col & 255;         // % DIM

    float4 v[NTPL];
    float lar = 1.f, lai = 0.f, lxr = 0.f, lxi = 0.f;
#pragma unroll
    for (int m = 0; m < NTPL; ++m) {
        v[m] = agg[((size_t)b * NT + lane * NTPL + m) * DIM + d];
        float nar = v[m].x * lar - v[m].y * lai;
        float nai = v[m].x * lai + v[m].y * lar;
        float nxr = v[m].x * lxr - v[m].y * lxi + v[m].z;
        float nxi = v[m].x * lxi + v[m].y * lxr + v[m].w;
        lar = nar; lai = nai; lxr = nxr; lxi = nxi;
    }

    float ar = lar, ai = lai, xr = lxr, xi = lxi;
#pragma unroll
    for (int off = 1; off < 64; off <<= 1) {
        float par = __shfl_up(ar, (unsigned)off, 64);
        float pai = __shfl_up(ai, (unsigned)off, 64);
        float pxr = __shfl_up(xr, (unsigned)off, 64);
        float pxi = __shfl_up(xi, (unsigned)off, 64);
        if (lane >= off) {
            float nar = ar * par - ai * pai;
            float nai = ar * pai + ai * par;
            float nxr = ar * pxr - ai * pxi + xr;
            float nxi = ar * pxi + ai * pxr + xi;
            ar = nar; ai = nai; xr = nxr; xi = nxi;
        }
    }

    float ear = __shfl_up(ar, 1u, 64);
    float eai = __shfl_up(ai, 1u, 64);
    float exr = __shfl_up(xr, 1u, 64);
    float exi = __shfl_up(xi, 1u, 64);
    if (lane == 0) { ear = 1.f; eai = 0.f; exr = 0.f; exi = 0.f; }

#pragma unroll
    for (int m = 0; m < NTPL; ++m) {
        agg[((size_t)b * NT + lane * NTPL + m) * DIM + d] =
            make_float4(exr, exi, 0.f, 0.f);
        float nar = v[m].x * ear - v[m].y * eai;
        float nai = v[m].x * eai + v[m].y * ear;
        float nxr = v[m].x * exr - v[m].y * exi + v[m].z;
        float nxi = v[m].x * exi + v[m].y * exr + v[m].w;
        ear = nar; eai = nai; exr = nxr; exi = nxi;
    }
}

// ---------------------------------------------------------------------------
// Kernel 3: seed y from tile prefix, recompute recurrence, write out.
// Plain unrolled loop (same shape as k1 now). Per t each lane writes one
// contiguous 16B nontemporal store ((d,re),(d,im),(d+1,re),(d+1,im)).
// ---------------------------------------------------------------------------
template <int NT, int T>
__global__ __launch_bounds__(256, 8) void k_apply(
    const float* __restrict__ Ar, const float* __restrict__ Ai,
    const float* __restrict__ Xr, const float* __restrict__ Xi,
    const float4* __restrict__ agg, float* __restrict__ outf)
{
    int half = threadIdx.x >> 7;
    int wl   = threadIdx.x & 127;
    int tile = blockIdx.x * 2 + half;
    int b = tile / NT;
    int j = tile - b * NT;
    int d = wl * 2;

    float yr[2], yi[2];
    size_t o = ((size_t)b * NT + j) * DIM + d;
    {
        float4 p0 = agg[o];
        float4 p1 = agg[o + 1];
        yr[0] = p0.x; yi[0] = p0.y;
        yr[1] = p1.x; yi[1] = p1.y;
    }

    size_t base = ((size_t)b * SEQ + (size_t)j * T) * DIM + d;

#pragma unroll
    for (int t = 0; t < T; ++t) {
        size_t idx = base + (size_t)t * DIM;
        float2 a_re = *(const float2*)(Ar + idx);
        float2 a_im = *(const float2*)(Ai + idx);
        float2 x_re = *(const float2*)(Xr + idx);
        float2 x_im = *(const float2*)(Xi + idx);
        const float* par = (const float*)&a_re;
        const float* pai = (const float*)&a_im;
        const float* pxr = (const float*)&x_re;
        const float* pxi = (const float*)&x_im;
#pragma unroll
        for (int k = 0; k < 2; ++k) {
            float nyr = par[k] * yr[k] - pai[k] * yi[k] + pxr[k];
            float nyi = par[k] * yi[k] + pai[k] * yr[k] + pxi[k];
            yr[k] = nyr; yi[k] = nyi;
        }
        floatx4 o1 = (floatx4){yr[0], yi[0], yr[1], yi[1]};
        __builtin_nontemporal_store(o1, (floatx4*)(outf + 2 * idx));
    }
}

extern "C" void kernel_launch(void* const* d_in, const int* in_sizes, int n_in,
                              void* d_out, int out_size, void* d_ws, size_t ws_size,
                              hipStream_t stream)
{
    const float* Ar = (const float*)d_in[0];
    const float* Ai = (const float*)d_in[1];
    const float* Xr = (const float*)d_in[2];
    const float* Xi = (const float*)d_in[3];
    float* outf = (float*)d_out;
    float4* agg = (float4*)d_ws;

    dim3 block(256);

    if (ws_size >= (size_t)BATCH * 256 * DIM * sizeof(float4)) {
        constexpr int NT = 256, T = SEQ / 256;   // T = 16
        dim3 grid1((BATCH * NT) / 2);            // 1024 blocks
        k_tile_agg<NT, T><<<grid1, block, 0, stream>>>(Ar, Ai, Xr, Xi, agg);
        k_scan_agg<NT><<<(BATCH * DIM) / 4, block, 0, stream>>>(agg);
        k_apply<NT, T><<<grid1, block, 0, stream>>>(Ar, Ai, Xr, Xi, agg, outf);
    } else {
        constexpr int NT = 64, T = SEQ / 64;     // T = 64
        dim3 grid1((BATCH * NT) / 2);
        k_tile_agg<NT, T><<<grid1, block, 0, stream>>>(Ar, Ai, Xr, Xi, agg);
        k_scan_agg<NT><<<(BATCH * DIM) / 4, block, 0, stream>>>(agg);
        k_apply<NT, T><<<grid1, block, 0, stream>>>(Ar, Ai, Xr, Xi, agg, outf);
    }
}